// Round 4
// baseline (261.660 us; speedup 1.0000x reference)
//
#include <hip/hip_runtime.h>

#define BATCH 16
#define TFRAMES 2000
#define BINS 513
#define NFFT 1024
#define STEP 256
#define OUT_LEN 512768            // (TFRAMES-1)*STEP + NFFT
#define M_TOTAL (BATCH*TFRAMES)   // 32000

// ---- legacy packed layout (fallback atomic path) ----
#define KP 1024
#define PAIRS 512
#define JPACK 128

// ---- symmetry-split layout (fast path) ----
// C[n] = sum_p Ar[p]*cos(2pi p n/1024), Ar[0]=re0/1024 (B_cos[n][0]=1), Ar[p]=re[p]/512
// S[n] = sum_p Ai[p]*sin(2pi p n/1024), Ai[p]=-im[p]/512, slot 0 dead (B_sin[n][0]=0)
// x[n]      = C[n]+S[n]+t,  x[1024-n] = C[n]-S[n]+t,  t=(-1)^n*re512/1024, n=0..511
// x[512]    = sum_k (-1)^k Ar[k] + re512/1024   (fused into pack wave-reduce)
#define KP2 512

typedef _Float16 f16x8 __attribute__((ext_vector_type(8)));
typedef float    f32x4 __attribute__((ext_vector_type(4)));

__device__ __forceinline__ void async_copy16(const void* g, void* l) {
    __builtin_amdgcn_global_load_lds(
        (const __attribute__((address_space(1))) unsigned*)g,
        (__attribute__((address_space(3))) unsigned*)l, 16, 0, 0);
}

// ---------------- fused fast-path pack kernel (A + B in one launch) ---------
#define PACKA_BLOCKS ((M_TOTAL * 64) / 256)   // 8000
#define PACKB_BLOCKS ((512 * 64) / 256)       // 128

__global__ __launch_bounds__(256) void pack_AB(const float* __restrict__ sre,
                                               const float* __restrict__ sim,
                                               const float* __restrict__ dcos,
                                               const float* __restrict__ dsin,
                                               const float* __restrict__ window,
                                               uint4* __restrict__ Ar,
                                               uint4* __restrict__ Ai,
                                               float* __restrict__ re512f,
                                               _Float16* __restrict__ frames,
                                               uint4* __restrict__ Bc,
                                               uint4* __restrict__ Bs)
{
    if (blockIdx.x < PACKA_BLOCKS) {
        // ---- A part: one wave per row m; thread j handles k = 8j..8j+7 ----
        const int idx = blockIdx.x * 256 + threadIdx.x;   // m*64 + j
        const int m = idx >> 6;
        const int j = idx & 63;
        const int k0 = j * 8;
        const size_t base = (size_t)m * BINS + k0;
        float ar[8], ai[8];
        #pragma unroll
        for (int i = 0; i < 8; i++) {
            ar[i] =  sre[base + i] * (1.0f/512.0f);
            ai[i] = -sim[base + i] * (1.0f/512.0f);
        }
        float r5 = 0.0f;
        if (j == 0) {
            ar[0] = sre[(size_t)m * BINS] * (1.0f/1024.0f);   // DC, B_cos[n][0]=1
            ai[0] = 0.0f;                                      // dead, B_sin[n][0]=0
            r5 = sre[(size_t)m * BINS + 512] * (1.0f/1024.0f);
            re512f[m] = r5;
        }
        union { _Float16 h[8]; uint4 u; } pr, pi;
        #pragma unroll
        for (int i = 0; i < 8; i++) { pr.h[i] = (_Float16)ar[i]; pi.h[i] = (_Float16)ai[i]; }
        Ar[idx] = pr.u;
        Ai[idx] = pi.u;

        // fused n=512 column: x[512] = sum_k (-1)^k Ar[k] + re512/1024
        float s = ar[0]-ar[1]+ar[2]-ar[3]+ar[4]-ar[5]+ar[6]-ar[7];
        #pragma unroll
        for (int off = 32; off > 0; off >>= 1) s += __shfl_xor(s, off);
        if (j == 0)
            frames[(size_t)m * NFFT + 512] = (_Float16)((s + r5) * window[512]);
    } else {
        // ---- B part ----
        const int idx = (blockIdx.x - PACKA_BLOCKS) * 256 + threadIdx.x;  // n*64 + j
        const int n = idx >> 6;
        const int j = idx & 63;
        const int k0 = j * 8;
        const size_t base = (size_t)n * NFFT + k0;
        union { _Float16 h[8]; uint4 u; } pc, ps;
        #pragma unroll
        for (int i = 0; i < 8; i++) {
            pc.h[i] = (_Float16)dcos[base + i];
            ps.h[i] = (_Float16)dsin[base + i];
        }
        if (j == 0) { pc.h[0] = (_Float16)1.0f; ps.h[0] = (_Float16)0.0f; }
        Bc[idx] = pc.u;
        Bs[idx] = ps.u;
    }
}

// ---------------- dual symmetry GEMM, BK=32, double-buffered prefetch -------
// R2's VERIFIED fused-row layout: LDS row = 128B = [re 32h | im 32h] (A) or
// [cos 32h | sin 32h] (B); 8-slot swizzle slot = chunk^(row&7), applied on the
// per-lane GLOBAL source (conflict-free, measured 0). Double-buffered:
// stage tile kt+1 into buf^1 BEFORE computing tile kt from buf, ONE
// __syncthreads per step (implicit vmcnt(0) lands the prefetch that flew
// under the compute; barrier makes buf safe to overwrite next step).
// LDS = 2 x 24 KB = 48 KB -> same 3 blocks/CU as round 3.
#define BM3 128
#define BN3 64
#define BK3 32    // halves per matrix per step -> 16 steps over KP2=512
#define NSTEP (KP2 / BK3)

__global__ __launch_bounds__(256, 3) void gemm_dual(
    const _Float16* __restrict__ Ar, const _Float16* __restrict__ Ai,
    const _Float16* __restrict__ Bc, const _Float16* __restrict__ Bs,
    const float* __restrict__ re512f, const float* __restrict__ window,
    _Float16* __restrict__ frames)
{
    __shared__ _Float16 LA[2][BM3 * 64];   // 2 x 16 KB, rows [re(32)|im(32)]
    __shared__ _Float16 LB[2][BN3 * 64];   // 2 x  8 KB, rows [cos(32)|sin(32)]

    const int raw = blockIdx.x;                    // 0..1999
    const int idx = (raw & 7) * 250 + (raw >> 3);  // XCD-grouping bijection
    const int mt = idx >> 3;                       // 0..249
    const int nt = idx & 7;                        // 0..7
    const int m0 = mt * BM3;
    const int n0 = nt * BN3;

    const int tid  = threadIdx.x;
    const int w    = tid >> 6;         // wave 0..3
    const int lane = tid & 63;
    const int wm   = w & 1;            // M-half (64 rows)
    const int wn   = w >> 1;           // N-half (32 cols)
    const int row16 = lane & 15;
    const int quad  = lane >> 4;

    // staging: srow 0..7, swizzled chunk slot (applied to global source);
    // chunks 0-3 carry matrix0 (re/cos), 4-7 carry matrix1 (im/sin)
    const int srow   = lane >> 3;
    const int schunk = (lane & 7) ^ srow;
    const _Float16* gA = ((schunk < 4) ? Ar : Ai)
                         + (size_t)(m0 + w*32 + srow) * KP2 + (schunk & 3) * 8;
    const _Float16* gB = ((schunk < 4) ? Bc : Bs)
                         + (size_t)(n0 + w*16 + srow) * KP2 + (schunk & 3) * 8;

    f32x4 aC[4][2] = {};
    f32x4 aS[4][2] = {};

    // prologue: stage tile 0 into buf 0
    {
        #pragma unroll
        for (int t = 0; t < 4; t++)
            async_copy16(gA + (size_t)t*8*KP2, &LA[0][(w*4 + t) * 512]);
        #pragma unroll
        for (int t = 0; t < 2; t++)
            async_copy16(gB + (size_t)t*8*KP2, &LB[0][(w*2 + t) * 512]);
    }
    __syncthreads();

    for (int kt = 0; kt < NSTEP; ++kt) {
        const int cur = kt & 1;

        // prefetch tile kt+1 into the other buffer (in flight under compute)
        if (kt < NSTEP-1) {
            const int k0 = (kt + 1) * BK3;
            #pragma unroll
            for (int t = 0; t < 4; t++)
                async_copy16(gA + (size_t)t*8*KP2 + k0, &LA[cur^1][(w*4 + t) * 512]);
            #pragma unroll
            for (int t = 0; t < 2; t++)
                async_copy16(gB + (size_t)t*8*KP2 + k0, &LB[cur^1][(w*2 + t) * 512]);
        }

        // compute tile kt from buf cur
        f16x8 ar[4], ai_[4], bc[2], bs_[2];
        #pragma unroll
        for (int i = 0; i < 4; i++) {
            const int rA = wm*64 + i*16 + row16;
            ar[i]  = *(const f16x8*)&LA[cur][rA * 64 + ((quad)     ^ (rA & 7)) * 8];
            ai_[i] = *(const f16x8*)&LA[cur][rA * 64 + ((4 + quad) ^ (rA & 7)) * 8];
        }
        #pragma unroll
        for (int j = 0; j < 2; j++) {
            const int rB = wn*32 + j*16 + row16;
            bc[j]  = *(const f16x8*)&LB[cur][rB * 64 + ((quad)     ^ (rB & 7)) * 8];
            bs_[j] = *(const f16x8*)&LB[cur][rB * 64 + ((4 + quad) ^ (rB & 7)) * 8];
        }
        #pragma unroll
        for (int i = 0; i < 4; i++)
            #pragma unroll
            for (int j = 0; j < 2; j++) {
                aC[i][j] = __builtin_amdgcn_mfma_f32_16x16x32_f16(ar[i],  bc[j],  aC[i][j], 0, 0, 0);
                aS[i][j] = __builtin_amdgcn_mfma_f32_16x16x32_f16(ai_[i], bs_[j], aS[i][j], 0, 0, 0);
            }

        // one barrier per step: drains prefetch (vmcnt) + fences buf reuse
        __syncthreads();
    }

    // Epilogue (verified round 2/3). C/D layout: col = lane&15 (-> n), row = quad*4 + reg.
    // x[n] = C+S+t (win[n]);  x[1024-n] = C-S+t (win[1024-n]), t = (-1)^n re512/1024.
    #pragma unroll
    for (int j = 0; j < 2; j++) {
        const int n = n0 + wn*32 + j*16 + row16;           // 0..511
        const float wpos = window[n];
        const float wneg = window[(NFFT - n) & (NFFT - 1)]; // n=0 unused
        #pragma unroll
        for (int i = 0; i < 4; i++) {
            const int mrow = m0 + wm*64 + i*16 + quad*4;
            const float4 r5v = *(const float4*)&re512f[mrow];
            const float r5a[4] = {r5v.x, r5v.y, r5v.z, r5v.w};
            const f32x4 c = aC[i][j];
            const f32x4 s = aS[i][j];
            #pragma unroll
            for (int r = 0; r < 4; r++) {
                const float t = (n & 1) ? -r5a[r] : r5a[r];
                const size_t mbase = (size_t)(mrow + r) * NFFT;
                frames[mbase + n] = (_Float16)((c[r] + s[r] + t) * wpos);
                if (n) frames[mbase + NFFT - n] = (_Float16)((c[r] - s[r] + t) * wneg);
            }
        }
    }
}

// ---------------- deterministic overlap-add gather (verified) ----------------
#define OLA_G 64096   // OUT_LEN/8
__global__ __launch_bounds__(256) void ola_gather(const _Float16* __restrict__ frames,
                                                  float* __restrict__ out)
{
    const int idx = blockIdx.x * 256 + threadIdx.x;   // b*OLA_G + r, exact grid
    const int b = idx / OLA_G;
    const int r = idx - b * OLA_G;
    const int s0 = r << 3;
    int tlo = (s0 - 768) >> 8;  if (tlo < 0) tlo = 0;
    int thi = s0 >> 8;          if (thi > TFRAMES-1) thi = TFRAMES-1;
    float sum[8] = {};
    for (int t = tlo; t <= thi; ++t) {
        const f16x8 f = *(const f16x8*)&frames[((size_t)b * TFRAMES + t) * NFFT + (s0 - (t << 8))];
        #pragma unroll
        for (int i = 0; i < 8; i++) sum[i] += (float)f[i];
    }
    f32x4* o = (f32x4*)(out + (size_t)b * OUT_LEN + s0);
    o[0] = (f32x4){sum[0], sum[1], sum[2], sum[3]};
    o[1] = (f32x4){sum[4], sum[5], sum[6], sum[7]};
}

// ---------------- legacy pack kernels (fallback atomic path) ----------------
__global__ __launch_bounds__(256) void pack_A(const float* __restrict__ sre,
                                              const float* __restrict__ sim,
                                              uint4* __restrict__ Au)
{
    const int idx = blockIdx.x * 256 + threadIdx.x;
    const int m = idx >> 7;
    const int j = idx & 127;
    const int k0 = j * 4;
    const size_t base = (size_t)m * BINS + k0;
    union { _Float16 h[8]; uint4 u; } pk;
    if (j == 0) {
        const float re0   = sre[(size_t)m * BINS];
        const float re512 = sre[(size_t)m * BINS + 512];
        pk.h[0] = (_Float16)(re0   * (1.0f/1024.0f));
        pk.h[1] = (_Float16)(re512 * (1.0f/1024.0f));
        #pragma unroll
        for (int i = 1; i < 4; i++) {
            pk.h[2*i]   = (_Float16)( sre[base + i] * (1.0f/512.0f));
            pk.h[2*i+1] = (_Float16)(-sim[base + i] * (1.0f/512.0f));
        }
    } else {
        #pragma unroll
        for (int i = 0; i < 4; i++) {
            pk.h[2*i]   = (_Float16)( sre[base + i] * (1.0f/512.0f));
            pk.h[2*i+1] = (_Float16)(-sim[base + i] * (1.0f/512.0f));
        }
    }
    Au[idx] = pk.u;
}

__global__ __launch_bounds__(256) void pack_B(const float* __restrict__ dcos,
                                              const float* __restrict__ dsin,
                                              unsigned* __restrict__ Bu)
{
    const int idx = blockIdx.x * 256 + threadIdx.x;
    const int n = idx >> 9;
    const int p = idx & 511;
    float b0, b1;
    if (p == 0) {
        b0 = 1.0f;
        b1 = (n & 1) ? -1.0f : 1.0f;
    } else {
        const size_t base = (size_t)n * NFFT + p;
        b0 = dcos[base];
        b1 = dsin[base];
    }
    union { _Float16 h[2]; unsigned u; } pk;
    pk.h[0] = (_Float16)b0;
    pk.h[1] = (_Float16)b1;
    Bu[idx] = pk.u;
}

// ---------------- legacy 128x128 MFMA GEMM (atomic fallback) ----------------
#define BM 128
#define BN 128
#define BK 64

__global__ __launch_bounds__(256, 3) void gemm_f16_atomic(const _Float16* __restrict__ A,
                                                          const _Float16* __restrict__ B,
                                                          const float* __restrict__ window,
                                                          float* __restrict__ out)
{
    __shared__ _Float16 As[BM * BK];
    __shared__ _Float16 Bs[BN * BK];

    const int raw = blockIdx.x;
    const int idx = (raw & 7) * 250 + (raw >> 3);
    const int mt = idx >> 3;
    const int nt = idx & 7;
    const int m0 = mt * BM;
    const int n0 = nt * BN;

    const int tid  = threadIdx.x;
    const int w    = tid >> 6;
    const int lane = tid & 63;
    const int wm   = w & 1;
    const int wn   = w >> 1;
    const int row16 = lane & 15;
    const int quad  = lane >> 4;

    const int srow   = lane >> 3;
    const int schunk = (lane & 7) ^ srow;
    const _Float16* gA = A + (size_t)(m0 + w*32 + srow) * KP + schunk * 8;
    const _Float16* gB = B + (size_t)(n0 + w*32 + srow) * KP + schunk * 8;

    f32x4 acc[4][4] = {};

    for (int k0 = 0; k0 < KP; k0 += BK) {
        #pragma unroll
        for (int t = 0; t < 4; t++) {
            async_copy16(gA + (size_t)t*8*KP + k0, As + (w*4 + t) * 512);
            async_copy16(gB + (size_t)t*8*KP + k0, Bs + (w*4 + t) * 512);
        }
        __syncthreads();
        #pragma unroll
        for (int c = 0; c < 2; c++) {
            f16x8 af[4], bf[4];
            #pragma unroll
            for (int i = 0; i < 4; i++) {
                const int rowA = wm*64 + i*16 + row16;
                const int chA  = (c*4 + quad) ^ (row16 & 7);
                af[i] = *(const f16x8*)&As[rowA * BK + chA * 8];
            }
            #pragma unroll
            for (int j = 0; j < 4; j++) {
                const int rowB = wn*64 + j*16 + row16;
                const int chB  = (c*4 + quad) ^ (row16 & 7);
                bf[j] = *(const f16x8*)&Bs[rowB * BK + chB * 8];
            }
            #pragma unroll
            for (int i = 0; i < 4; i++)
                #pragma unroll
                for (int j = 0; j < 4; j++)
                    acc[i][j] = __builtin_amdgcn_mfma_f32_16x16x32_f16(af[i], bf[j], acc[i][j], 0, 0, 0);
        }
        __syncthreads();
    }

    #pragma unroll
    for (int j = 0; j < 4; j++) {
        const int n = n0 + wn*64 + j*16 + row16;
        const float win = window[n];
        #pragma unroll
        for (int i = 0; i < 4; i++) {
            const int mrow = m0 + wm*64 + i*16 + quad*4;
            const f32x4 c = acc[i][j];
            #pragma unroll
            for (int r = 0; r < 4; r++) {
                const int m = mrow + r;
                const int b = m / TFRAMES;
                const int t = m - b * TFRAMES;
                atomicAdd(&out[(size_t)b * OUT_LEN + (size_t)t * STEP + n], c[r] * win);
            }
        }
    }
}

// ---------------- round-1 fp32 fallback (known-correct) ----------------
#define MT 64
#define NT 64
#define KT 16
#define PAD 4
__global__ __launch_bounds__(256) void istft_gemm_ola_f32(
    const float* __restrict__ sre, const float* __restrict__ sim,
    const float* __restrict__ dcos, const float* __restrict__ dsin,
    const float* __restrict__ window, float* __restrict__ out)
{
    __shared__ float As_re[KT][MT + PAD];
    __shared__ float As_im[KT][MT + PAD];
    __shared__ float Bs_c[KT][NT + PAD];
    __shared__ float Bs_s[KT][NT + PAD];
    const int ntile = blockIdx.x & 15;
    const int mtile = blockIdx.x >> 4;
    const int m0 = mtile * MT, n0 = ntile * NT;
    const int tid = threadIdx.x;
    const int tx = tid & 15, ty = tid >> 4;
    const int lcol = tid & 15, lrow = tid >> 4;
    float acc[4][4] = {};
    for (int k0 = 0; k0 < BINS; k0 += KT) {
        const int k = k0 + lcol;
        const bool kvalid = (k < BINS);
        const float w = kvalid ? ((k == 0 || k == 512) ? (1.0f/1024.0f) : (2.0f/1024.0f)) : 0.0f;
        #pragma unroll
        for (int i = 0; i < 4; i++) {
            const int m = m0 + lrow + i*16;
            const size_t base = (size_t)m * BINS + k;
            As_re[lcol][lrow + i*16] = kvalid ?  w * sre[base] : 0.0f;
            As_im[lcol][lrow + i*16] = kvalid ? -w * sim[base] : 0.0f;
        }
        #pragma unroll
        for (int i = 0; i < 4; i++) {
            const int n = n0 + lrow + i*16;
            const size_t base = (size_t)n * NFFT + k;
            Bs_c[lcol][lrow + i*16] = kvalid ? dcos[base] : 0.0f;
            Bs_s[lcol][lrow + i*16] = kvalid ? dsin[base] : 0.0f;
        }
        __syncthreads();
        #pragma unroll
        for (int kk = 0; kk < KT; kk++) {
            const float4 ar = *(const float4*)&As_re[kk][ty*4];
            const float4 ai = *(const float4*)&As_im[kk][ty*4];
            const float4 bc = *(const float4*)&Bs_c[kk][tx*4];
            const float4 bs = *(const float4*)&Bs_s[kk][tx*4];
            const float a_r[4] = {ar.x, ar.y, ar.z, ar.w};
            const float a_i[4] = {ai.x, ai.y, ai.z, ai.w};
            const float b_c[4] = {bc.x, bc.y, bc.z, bc.w};
            const float b_s[4] = {bs.x, bs.y, bs.z, bs.w};
            #pragma unroll
            for (int i = 0; i < 4; i++)
                #pragma unroll
                for (int j = 0; j < 4; j++)
                    acc[i][j] += a_r[i]*b_c[j] + a_i[i]*b_s[j];
        }
        __syncthreads();
    }
    #pragma unroll
    for (int i = 0; i < 4; i++) {
        const int m = m0 + ty*4 + i;
        const int b = m / TFRAMES;
        const int t = m - b * TFRAMES;
        const size_t obase = (size_t)b * OUT_LEN + (size_t)t * STEP;
        #pragma unroll
        for (int j = 0; j < 4; j++) {
            const int n = n0 + tx*4 + j;
            atomicAdd(&out[obase + n], acc[i][j] * window[n]);
        }
    }
}

// ---------------- launch ----------------
extern "C" void kernel_launch(void* const* d_in, const int* in_sizes, int n_in,
                              void* d_out, int out_size, void* d_ws, size_t ws_size,
                              hipStream_t stream) {
    const float* sre    = (const float*)d_in[0];
    const float* sim    = (const float*)d_in[1];
    const float* dcos   = (const float*)d_in[2];
    const float* dsin   = (const float*)d_in[3];
    const float* window = (const float*)d_in[4];
    float* out = (float*)d_out;

    // fast-path workspace layout
    const size_t WS_AR = (size_t)M_TOTAL * KP2 * sizeof(_Float16);    // 32,768,000
    const size_t WS_AI = WS_AR;
    const size_t WS_R5 = (size_t)M_TOTAL * sizeof(float);             //    128,000
    const size_t WS_BC = (size_t)512 * KP2 * sizeof(_Float16);        //    524,288
    const size_t WS_BS = WS_BC;
    const size_t WS_FR = (size_t)M_TOTAL * NFFT * sizeof(_Float16);   // 65,536,000
    const size_t NEED  = WS_AR + WS_AI + WS_R5 + WS_BC + WS_BS + WS_FR;

    // legacy atomic-path workspace
    const size_t WS_A = (size_t)M_TOTAL * KP * sizeof(_Float16);
    const size_t WS_B = (size_t)NFFT    * KP * sizeof(_Float16);

    if (ws_size >= NEED) {
        char* p = (char*)d_ws;
        _Float16* Ar = (_Float16*)p;  p += WS_AR;
        _Float16* Ai = (_Float16*)p;  p += WS_AI;
        float*    r5 = (float*)p;     p += WS_R5;
        _Float16* Bc = (_Float16*)p;  p += WS_BC;
        _Float16* Bs = (_Float16*)p;  p += WS_BS;
        _Float16* fr = (_Float16*)p;

        pack_AB<<<PACKA_BLOCKS + PACKB_BLOCKS, 256, 0, stream>>>(
            sre, sim, dcos, dsin, window,
            (uint4*)Ar, (uint4*)Ai, r5, fr, (uint4*)Bc, (uint4*)Bs);

        const int grid = (M_TOTAL / BM3) * (KP2 / BN3);   // 250 * 8 = 2000
        gemm_dual<<<grid, 256, 0, stream>>>(Ar, Ai, Bc, Bs, r5, window, fr);
        ola_gather<<<(BATCH * OUT_LEN) / 2048, 256, 0, stream>>>(fr, out);
    } else if (ws_size >= WS_A + WS_B) {
        hipMemsetAsync(out, 0, (size_t)out_size * sizeof(float), stream);
        _Float16* Apk = (_Float16*)d_ws;
        _Float16* Bpk = (_Float16*)((char*)d_ws + WS_A);
        pack_A<<<(M_TOTAL * JPACK) / 256, 256, 0, stream>>>(sre, sim, (uint4*)Apk);
        pack_B<<<(NFFT * PAIRS) / 256, 256, 0, stream>>>(dcos, dsin, (unsigned*)Bpk);
        const int grid = (M_TOTAL / BM) * (NFFT / BN);
        gemm_f16_atomic<<<grid, 256, 0, stream>>>(Apk, Bpk, window, out);
    } else {
        hipMemsetAsync(out, 0, (size_t)out_size * sizeof(float), stream);
        const int grid = (M_TOTAL / MT) * (NFFT / NT);
        istft_gemm_ola_f32<<<grid, 256, 0, stream>>>(sre, sim, dcos, dsin, window, out);
    }
}